// Round 4
// baseline (470.815 us; speedup 1.0000x reference)
//
#include <hip/hip_runtime.h>

typedef __bf16  bf16x8 __attribute__((ext_vector_type(8)));
typedef float   f32x4  __attribute__((ext_vector_type(4)));
typedef unsigned short u16;

__device__ __forceinline__ u16 f2bf(float f) {
  union { float f; unsigned u32; } c; c.f = f;
  unsigned r = c.u32 + 0x7fffu + ((c.u32 >> 16) & 1u);   // RNE
  return (u16)(r >> 16);
}

// async global->LDS, 16B per lane; HW places lane i at (wave-uniform base)+i*16
__device__ __forceinline__ void async16(const void* g, void* l) {
  __builtin_amdgcn_global_load_lds(
      (const __attribute__((address_space(1))) unsigned*)g,
      (__attribute__((address_space(3))) unsigned*)l, 16, 0, 0);
}

// ---------------- circulant builder: Ct[n*512+k] = w[(n-k)&511] / sqrt(512)
__global__ __launch_bounds__(256) void build_ct(const float* __restrict__ w,
                                                u16* __restrict__ ct) {
  int idx = blockIdx.x * 256 + threadIdx.x;          // 0..262143
  int n = idx >> 9, k = idx & 511;
  float v = w[(n - k) & 511] * 0.04419417382415922f; // 1/sqrt(512)
  ct[idx] = f2bf(v);
}

// ---------------- transpose + cast: out(bf16)[c][r] = in(fp32)[r][c]
__global__ __launch_bounds__(256) void transpose_w(const float* __restrict__ in,
                                                   u16* __restrict__ out,
                                                   int R, int C) {
  __shared__ float tile[32][33];
  int bx = blockIdx.x * 32;   // col base in `in`
  int by = blockIdx.y * 32;   // row base in `in`
  int tx = threadIdx.x & 31, ty = threadIdx.x >> 5;
#pragma unroll
  for (int r = ty; r < 32; r += 8)
    tile[r][tx] = in[(size_t)(by + r) * C + bx + tx];
  __syncthreads();
#pragma unroll
  for (int r = ty; r < 32; r += 8)
    out[(size_t)(bx + r) * R + by + tx] = f2bf(tile[tx][r]);
}

// ---------------- LayerNorm over a [64,512]=32768 fp32 slab -> bf16 out
__global__ __launch_bounds__(256) void ln2d_kernel(const float* __restrict__ x,
                                                   const float* __restrict__ g,
                                                   const float* __restrict__ beta,
                                                   u16* __restrict__ out) {
  const int tid = threadIdx.x;
  const size_t base = (size_t)blockIdx.x * 32768;
  float s = 0.f, ss = 0.f;
  for (int i = tid * 4; i < 32768; i += 1024) {
    float4 v = *(const float4*)(x + base + i);
    s  += v.x + v.y + v.z + v.w;
    ss += v.x * v.x + v.y * v.y + v.z * v.z + v.w * v.w;
  }
#pragma unroll
  for (int off = 32; off > 0; off >>= 1) {
    s += __shfl_down(s, off, 64);
    ss += __shfl_down(ss, off, 64);
  }
  __shared__ float red[8];
  int wave = tid >> 6, lane = tid & 63;
  if (lane == 0) { red[wave] = s; red[4 + wave] = ss; }
  __syncthreads();
  float S = red[0] + red[1] + red[2] + red[3];
  float SS = red[4] + red[5] + red[6] + red[7];
  const float inv = 1.0f / 32768.0f;
  float mu = S * inv;
  float var = SS * inv - mu * mu;
  float rs = rsqrtf(var + 1e-5f);
  for (int i = tid * 4; i < 32768; i += 1024) {
    float4 v = *(const float4*)(x + base + i);
    float4 gv = *(const float4*)(g + i);
    float4 bv = *(const float4*)(beta + i);
    uint2 o;
    o.x = (unsigned)f2bf((v.x - mu) * rs * gv.x + bv.x) |
          ((unsigned)f2bf((v.y - mu) * rs * gv.y + bv.y) << 16);
    o.y = (unsigned)f2bf((v.z - mu) * rs * gv.z + bv.z) |
          ((unsigned)f2bf((v.w - mu) * rs * gv.w + bv.w) << 16);
    *(uint2*)(out + base + i) = o;
  }
}

// ---------------- GEMM: C[M,N] = A[M,K](bf16) @ Bt[N,K](bf16)^T
// LDS layout is XOR-swizzled in 16B chunks: slot (row, c) holds global
// k-chunk c ^ ((row>>1)&3). Staging stays lane-linear (async16-compatible);
// fragment reads become 2-way-conflict (free) instead of 8-way.
// MODE 0: plain, fp32 out
// MODE 1: +bias(fp32), ReLU, bf16 out
// MODE 2: +bias(fp32), +resid(fp32), fp32 out
template <int MODE>
__global__ __launch_bounds__(256) void gemm_bt(
    const u16* __restrict__ A, const u16* __restrict__ Bt,
    const float* __restrict__ bias, const float* __restrict__ resid,
    float* __restrict__ Cf, u16* __restrict__ Cb, int M, int N, int K) {
  __shared__ u16 As[128 * 32];
  __shared__ u16 Bs[128 * 32];
  const int tid = threadIdx.x;
  const int wave = tid >> 6, lane = tid & 63;
  const int quad = lane >> 4, l16 = lane & 15;
  const int wm = (wave >> 1) * 64, wn = (wave & 1) * 64;
  const int m0 = blockIdx.x * 128, n0 = blockIdx.y * 128;

  f32x4 acc[4][4];
#pragma unroll
  for (int i = 0; i < 4; ++i)
#pragma unroll
    for (int j = 0; j < 4; ++j) acc[i][j] = (f32x4){0.f, 0.f, 0.f, 0.f};

  const int carow = tid >> 2;                      // 0..63
  const int chunk = tid & 3;                       // 16B chunk slot in LDS row
  const int gcol = ((chunk ^ ((carow >> 1) & 3)) * 8);  // swizzled global k-col
  // LDS slot offsets (u16 units): lane-linear per wave, async16-compatible
  const int lslot0 = carow * 32 + chunk * 8;
  const int lslot1 = (carow + 64) * 32 + chunk * 8;

  const u16* ag0 = A + (size_t)(m0 + carow) * K + gcol;
  const u16* ag1 = A + (size_t)(m0 + carow + 64) * K + gcol;
  const u16* bg0 = Bt + (size_t)(n0 + carow) * K + gcol;
  const u16* bg1 = Bt + (size_t)(n0 + carow + 64) * K + gcol;

  // fragment read addresses (swizzle applied per row)
  int raddrA[4], raddrB[4];
#pragma unroll
  for (int i = 0; i < 4; ++i) {
    const int rowA = wm + i * 16 + l16;
    raddrA[i] = rowA * 32 + (quad ^ ((rowA >> 1) & 3)) * 8;
    const int rowB = wn + i * 16 + l16;
    raddrB[i] = rowB * 32 + (quad ^ ((rowB >> 1) & 3)) * 8;
  }

  for (int k0 = 0; k0 < K; k0 += 32) {
    __syncthreads();   // previous iteration's ds_reads done before overwrite
    async16(ag0 + k0, &As[lslot0]);
    async16(ag1 + k0, &As[lslot1]);
    async16(bg0 + k0, &Bs[lslot0]);
    async16(bg1 + k0, &Bs[lslot1]);
    __syncthreads();   // drains vmcnt: staged data visible to all waves

    bf16x8 af[4], bfr[4];
#pragma unroll
    for (int i = 0; i < 4; ++i) af[i] = *(const bf16x8*)&As[raddrA[i]];
#pragma unroll
    for (int j = 0; j < 4; ++j) bfr[j] = *(const bf16x8*)&Bs[raddrB[j]];
#pragma unroll
    for (int i = 0; i < 4; ++i)
#pragma unroll
      for (int j = 0; j < 4; ++j)
        acc[i][j] = __builtin_amdgcn_mfma_f32_16x16x32_bf16(af[i], bfr[j],
                                                            acc[i][j], 0, 0, 0);
  }

#pragma unroll
  for (int j = 0; j < 4; ++j) {
    const int col = n0 + wn + j * 16 + l16;
    float bj = 0.f;
    if (MODE >= 1) bj = bias[col];
#pragma unroll
    for (int i = 0; i < 4; ++i) {
      const int rowb = m0 + wm + i * 16 + quad * 4;
#pragma unroll
      for (int r = 0; r < 4; ++r) {
        float v = acc[i][j][r] + bj;
        if (MODE == 1) v = fmaxf(v, 0.f);
        size_t idx = (size_t)(rowb + r) * N + col;
        if (MODE == 2) v += resid[idx];
        if (MODE == 1) Cb[idx] = f2bf(v);
        else           Cf[idx] = v;
      }
    }
  }
}

extern "C" void kernel_launch(void* const* d_in, const int* in_sizes, int n_in,
                              void* d_out, int out_size, void* d_ws,
                              size_t ws_size, hipStream_t stream) {
  const float* x    = (const float*)d_in[0];  // [512,64,512] fp32
  const float* w    = (const float*)d_in[1];  // [1,512]
  const float* ln1w = (const float*)d_in[2];  // [64,512]
  const float* ln1b = (const float*)d_in[3];
  const float* ln2w = (const float*)d_in[4];
  const float* ln2b = (const float*)d_in[5];
  const float* w1   = (const float*)d_in[6];  // [512,2048]
  const float* b1   = (const float*)d_in[7];  // [2048]
  const float* w2   = (const float*)d_in[8];  // [2048,512]
  const float* b2   = (const float*)d_in[9];  // [512]
  float* out = (float*)d_out;                 // [512,64,512] fp32

  char* ws = (char*)d_ws;
  // y overlaps h1+h2 (both dead before FFN1 writes y)
  u16*   y   = (u16*)(ws);                  // [32768,2048] bf16  134,217,728 B @ 0
  u16*   h1  = (u16*)(ws);                  // [32768,512]  bf16   33,554,432 B @ 0
  float* h2  = (float*)(ws + 33554432);     // [32768,512]  fp32   67,108,864 B @ 33,554,432
  u16*   h3  = (u16*)(ws + 134217728);      // [32768,512]  bf16   33,554,432 B @ 134,217,728
  u16*   ct  = (u16*)(ws + 167772160);      // [512,512]    bf16      524,288 B
  u16*   w1t = (u16*)(ws + 168296448);      // [2048,512]   bf16    2,097,152 B
  u16*   w2t = (u16*)(ws + 170393600);      // [512,2048]   bf16    2,097,152 B
  // peak ws use: 172,490,752 B

  build_ct<<<1024, 256, 0, stream>>>(w, ct);
  // w1 [512,2048] -> w1t [2048,512]
  transpose_w<<<dim3(64, 16), 256, 0, stream>>>(w1, w1t, 512, 2048);
  // w2 [2048,512] -> w2t [512,2048]
  transpose_w<<<dim3(16, 64), 256, 0, stream>>>(w2, w2t, 2048, 512);

  // LN1: x(fp32) -> h1(bf16)
  ln2d_kernel<<<512, 256, 0, stream>>>(x, ln1w, ln1b, h1);
  // freq filter: h2(fp32) = h1 @ C  (circulant, ortho scale folded into ct)
  gemm_bt<0><<<dim3(256, 4), 256, 0, stream>>>(h1, ct, nullptr, nullptr,
                                               h2, nullptr, 32768, 512, 512);
  // LN2: h2(fp32) -> h3(bf16)
  ln2d_kernel<<<512, 256, 0, stream>>>(h2, ln2w, ln2b, h3);
  // FFN1: y(bf16) = relu(h3 @ w1 + b1)
  gemm_bt<1><<<dim3(256, 16), 256, 0, stream>>>(h3, w1t, b1, nullptr,
                                                nullptr, y, 32768, 2048, 512);
  // FFN2 + residual: out(fp32) = y @ w2 + b2 + x
  gemm_bt<2><<<dim3(256, 4), 256, 0, stream>>>(y, w2t, b2, x,
                                               out, nullptr, 32768, 512, 2048);
}

// Round 5
// 431.975 us; speedup vs baseline: 1.0899x; 1.0899x over previous
//
#include <hip/hip_runtime.h>

typedef __bf16  bf16x8 __attribute__((ext_vector_type(8)));
typedef float   f32x4  __attribute__((ext_vector_type(4)));
typedef unsigned short u16;

__device__ __forceinline__ u16 f2bf(float f) {
  union { float f; unsigned u32; } c; c.f = f;
  unsigned r = c.u32 + 0x7fffu + ((c.u32 >> 16) & 1u);   // RNE
  return (u16)(r >> 16);
}

// async global->LDS, 16B per lane; HW places lane i at (wave-uniform base)+i*16
__device__ __forceinline__ void async16(const void* g, void* l) {
  __builtin_amdgcn_global_load_lds(
      (const __attribute__((address_space(1))) unsigned*)g,
      (__attribute__((address_space(3))) unsigned*)l, 16, 0, 0);
}

// ---------------- circulant builder: Ct[n*512+k] = w[(n-k)&511] / sqrt(512)
__global__ __launch_bounds__(256) void build_ct(const float* __restrict__ w,
                                                u16* __restrict__ ct) {
  int idx = blockIdx.x * 256 + threadIdx.x;          // 0..262143
  int n = idx >> 9, k = idx & 511;
  float v = w[(n - k) & 511] * 0.04419417382415922f; // 1/sqrt(512)
  ct[idx] = f2bf(v);
}

// ---------------- transpose + cast: out(bf16)[c][r] = in(fp32)[r][c]
__global__ __launch_bounds__(256) void transpose_w(const float* __restrict__ in,
                                                   u16* __restrict__ out,
                                                   int R, int C) {
  __shared__ float tile[32][33];
  int bx = blockIdx.x * 32;   // col base in `in`
  int by = blockIdx.y * 32;   // row base in `in`
  int tx = threadIdx.x & 31, ty = threadIdx.x >> 5;
#pragma unroll
  for (int r = ty; r < 32; r += 8)
    tile[r][tx] = in[(size_t)(by + r) * C + bx + tx];
  __syncthreads();
#pragma unroll
  for (int r = ty; r < 32; r += 8)
    out[(size_t)(bx + r) * R + by + tx] = f2bf(tile[tx][r]);
}

// ---------------- LayerNorm over a [64,512]=32768 fp32 slab -> bf16 out
__global__ __launch_bounds__(256) void ln2d_kernel(const float* __restrict__ x,
                                                   const float* __restrict__ g,
                                                   const float* __restrict__ beta,
                                                   u16* __restrict__ out) {
  const int tid = threadIdx.x;
  const size_t base = (size_t)blockIdx.x * 32768;
  float s = 0.f, ss = 0.f;
  for (int i = tid * 4; i < 32768; i += 1024) {
    float4 v = *(const float4*)(x + base + i);
    s  += v.x + v.y + v.z + v.w;
    ss += v.x * v.x + v.y * v.y + v.z * v.z + v.w * v.w;
  }
#pragma unroll
  for (int off = 32; off > 0; off >>= 1) {
    s += __shfl_down(s, off, 64);
    ss += __shfl_down(ss, off, 64);
  }
  __shared__ float red[8];
  int wave = tid >> 6, lane = tid & 63;
  if (lane == 0) { red[wave] = s; red[4 + wave] = ss; }
  __syncthreads();
  float S = red[0] + red[1] + red[2] + red[3];
  float SS = red[4] + red[5] + red[6] + red[7];
  const float inv = 1.0f / 32768.0f;
  float mu = S * inv;
  float var = SS * inv - mu * mu;
  float rs = rsqrtf(var + 1e-5f);
  for (int i = tid * 4; i < 32768; i += 1024) {
    float4 v = *(const float4*)(x + base + i);
    float4 gv = *(const float4*)(g + i);
    float4 bv = *(const float4*)(beta + i);
    uint2 o;
    o.x = (unsigned)f2bf((v.x - mu) * rs * gv.x + bv.x) |
          ((unsigned)f2bf((v.y - mu) * rs * gv.y + bv.y) << 16);
    o.y = (unsigned)f2bf((v.z - mu) * rs * gv.z + bv.z) |
          ((unsigned)f2bf((v.w - mu) * rs * gv.w + bv.w) << 16);
    *(uint2*)(out + base + i) = o;
  }
}

// ---------------- GEMM: C[M,N] = A[M,K](bf16) @ Bt[N,K](bf16)^T
// LDS 16B-chunk XOR swizzle: slot (row,c) holds global k-chunk c^((row>>1)&3).
// Staging stays lane-linear (async16-compatible); reads are conflict-free.
// Read-side XOR term reduces to (l16>>1)&3 (row bits 1..2 come only from l16).
// MODE 0: plain, fp32 out
// MODE 1: +bias(fp32), ReLU, bf16 out
// MODE 2: +bias(fp32), +resid(fp32), fp32 out
template <int MODE>
__global__ __launch_bounds__(256, 4) void gemm_bt(
    const u16* __restrict__ A, const u16* __restrict__ Bt,
    const float* __restrict__ bias, const float* __restrict__ resid,
    float* __restrict__ Cf, u16* __restrict__ Cb, int M, int N, int K) {
  __shared__ u16 As[128 * 32];
  __shared__ u16 Bs[128 * 32];
  const int tid = threadIdx.x;
  const int wave = tid >> 6, lane = tid & 63;
  const int quad = lane >> 4, l16 = lane & 15;
  const int wm = (wave >> 1) * 64, wn = (wave & 1) * 64;
  const int m0 = blockIdx.x * 128, n0 = blockIdx.y * 128;

  f32x4 acc[4][4];
#pragma unroll
  for (int i = 0; i < 4; ++i)
#pragma unroll
    for (int j = 0; j < 4; ++j) acc[i][j] = (f32x4){0.f, 0.f, 0.f, 0.f};

  const int carow = tid >> 2;                           // 0..63
  const int chunk = tid & 3;                            // 16B slot in LDS row
  const int gcol = (chunk ^ ((carow >> 1) & 3)) * 8;    // swizzled global k-col
  const int lslot0 = carow * 32 + chunk * 8;            // lane-linear LDS slots
  const int lslot1 = (carow + 64) * 32 + chunk * 8;
  const int sw = (quad ^ ((l16 >> 1) & 3)) * 8;         // read-side swizzle

  const u16* ag0 = A + (size_t)(m0 + carow) * K + gcol;
  const u16* ag1 = A + (size_t)(m0 + carow + 64) * K + gcol;
  const u16* bg0 = Bt + (size_t)(n0 + carow) * K + gcol;
  const u16* bg1 = Bt + (size_t)(n0 + carow + 64) * K + gcol;

  for (int k0 = 0; k0 < K; k0 += 32) {
    __syncthreads();   // previous iteration's ds_reads done before overwrite
    async16(ag0 + k0, &As[lslot0]);
    async16(ag1 + k0, &As[lslot1]);
    async16(bg0 + k0, &Bs[lslot0]);
    async16(bg1 + k0, &Bs[lslot1]);
    __syncthreads();   // drains vmcnt: staged data visible to all waves

    bf16x8 af[4], bfr[4];
#pragma unroll
    for (int i = 0; i < 4; ++i)
      af[i] = *(const bf16x8*)&As[(wm + i * 16 + l16) * 32 + sw];
#pragma unroll
    for (int j = 0; j < 4; ++j)
      bfr[j] = *(const bf16x8*)&Bs[(wn + j * 16 + l16) * 32 + sw];
#pragma unroll
    for (int i = 0; i < 4; ++i)
#pragma unroll
      for (int j = 0; j < 4; ++j)
        acc[i][j] = __builtin_amdgcn_mfma_f32_16x16x32_bf16(af[i], bfr[j],
                                                            acc[i][j], 0, 0, 0);
  }

#pragma unroll
  for (int j = 0; j < 4; ++j) {
    const int col = n0 + wn + j * 16 + l16;
    float bj = 0.f;
    if (MODE >= 1) bj = bias[col];
#pragma unroll
    for (int i = 0; i < 4; ++i) {
      const int rowb = m0 + wm + i * 16 + quad * 4;
#pragma unroll
      for (int r = 0; r < 4; ++r) {
        float v = acc[i][j][r] + bj;
        if (MODE == 1) v = fmaxf(v, 0.f);
        size_t idx = (size_t)(rowb + r) * N + col;
        if (MODE == 2) v += resid[idx];
        if (MODE == 1) Cb[idx] = f2bf(v);
        else           Cf[idx] = v;
      }
    }
  }
}

extern "C" void kernel_launch(void* const* d_in, const int* in_sizes, int n_in,
                              void* d_out, int out_size, void* d_ws,
                              size_t ws_size, hipStream_t stream) {
  const float* x    = (const float*)d_in[0];  // [512,64,512] fp32
  const float* w    = (const float*)d_in[1];  // [1,512]
  const float* ln1w = (const float*)d_in[2];  // [64,512]
  const float* ln1b = (const float*)d_in[3];
  const float* ln2w = (const float*)d_in[4];
  const float* ln2b = (const float*)d_in[5];
  const float* w1   = (const float*)d_in[6];  // [512,2048]
  const float* b1   = (const float*)d_in[7];  // [2048]
  const float* w2   = (const float*)d_in[8];  // [2048,512]
  const float* b2   = (const float*)d_in[9];  // [512]
  float* out = (float*)d_out;                 // [512,64,512] fp32

  char* ws = (char*)d_ws;
  // y overlaps h1+h2 (both dead before FFN1 writes y)
  u16*   y   = (u16*)(ws);                  // [32768,2048] bf16  134,217,728 B @ 0
  u16*   h1  = (u16*)(ws);                  // [32768,512]  bf16   33,554,432 B @ 0
  float* h2  = (float*)(ws + 33554432);     // [32768,512]  fp32   67,108,864 B @ 33,554,432
  u16*   h3  = (u16*)(ws + 134217728);      // [32768,512]  bf16   33,554,432 B @ 134,217,728
  u16*   ct  = (u16*)(ws + 167772160);      // [512,512]    bf16      524,288 B
  u16*   w1t = (u16*)(ws + 168296448);      // [2048,512]   bf16    2,097,152 B
  u16*   w2t = (u16*)(ws + 170393600);      // [512,2048]   bf16    2,097,152 B
  // peak ws use: 172,490,752 B

  build_ct<<<1024, 256, 0, stream>>>(w, ct);
  // w1 [512,2048] -> w1t [2048,512]
  transpose_w<<<dim3(64, 16), 256, 0, stream>>>(w1, w1t, 512, 2048);
  // w2 [2048,512] -> w2t [512,2048]
  transpose_w<<<dim3(16, 64), 256, 0, stream>>>(w2, w2t, 2048, 512);

  // LN1: x(fp32) -> h1(bf16)
  ln2d_kernel<<<512, 256, 0, stream>>>(x, ln1w, ln1b, h1);
  // freq filter: h2(fp32) = h1 @ C  (circulant, ortho scale folded into ct)
  gemm_bt<0><<<dim3(256, 4), 256, 0, stream>>>(h1, ct, nullptr, nullptr,
                                               h2, nullptr, 32768, 512, 512);
  // LN2: h2(fp32) -> h3(bf16)
  ln2d_kernel<<<512, 256, 0, stream>>>(h2, ln2w, ln2b, h3);
  // FFN1: y(bf16) = relu(h3 @ w1 + b1)
  gemm_bt<1><<<dim3(256, 16), 256, 0, stream>>>(h3, w1t, b1, nullptr,
                                                nullptr, y, 32768, 2048, 512);
  // FFN2 + residual: out(fp32) = y @ w2 + b2 + x
  gemm_bt<2><<<dim3(256, 4), 256, 0, stream>>>(y, w2t, b2, x,
                                               out, nullptr, 32768, 512, 2048);
}

// Round 6
// 389.671 us; speedup vs baseline: 1.2082x; 1.1086x over previous
//
#include <hip/hip_runtime.h>

typedef __bf16  bf16x8 __attribute__((ext_vector_type(8)));
typedef float   f32x4  __attribute__((ext_vector_type(4)));
typedef unsigned short u16;

__device__ __forceinline__ u16 f2bf(float f) {
  union { float f; unsigned u32; } c; c.f = f;
  unsigned r = c.u32 + 0x7fffu + ((c.u32 >> 16) & 1u);   // RNE
  return (u16)(r >> 16);
}
__device__ __forceinline__ float bf2f(u16 u) {
  union { unsigned u32; float f; } c; c.u32 = (unsigned)u << 16; return c.f;
}

// async global->LDS, 16B per lane; HW places lane i at (wave-uniform base)+i*16
__device__ __forceinline__ void async16(const void* g, void* l) {
  __builtin_amdgcn_global_load_lds(
      (const __attribute__((address_space(1))) unsigned*)g,
      (__attribute__((address_space(3))) unsigned*)l, 16, 0, 0);
}

// ---------------- circulant builder: Ct[n*512+k] = w[(n-k)&511] / sqrt(512)
__global__ __launch_bounds__(256) void build_ct(const float* __restrict__ w,
                                                u16* __restrict__ ct) {
  int idx = blockIdx.x * 256 + threadIdx.x;          // 0..262143
  int n = idx >> 9, k = idx & 511;
  float v = w[(n - k) & 511] * 0.04419417382415922f; // 1/sqrt(512)
  ct[idx] = f2bf(v);
}

// ---------------- transpose + cast: out(bf16)[c][r] = in(fp32)[r][c]
__global__ __launch_bounds__(256) void transpose_w(const float* __restrict__ in,
                                                   u16* __restrict__ out,
                                                   int R, int C) {
  __shared__ float tile[32][33];
  int bx = blockIdx.x * 32;
  int by = blockIdx.y * 32;
  int tx = threadIdx.x & 31, ty = threadIdx.x >> 5;
#pragma unroll
  for (int r = ty; r < 32; r += 8)
    tile[r][tx] = in[(size_t)(by + r) * C + bx + tx];
  __syncthreads();
#pragma unroll
  for (int r = ty; r < 32; r += 8)
    out[(size_t)(bx + r) * R + by + tx] = f2bf(tile[tx][r]);
}

// ---------------- LayerNorm [64,512] slab, fp32 in, single global read
// 512 threads; each thread holds 64 floats (16 float4) in registers.
__global__ __launch_bounds__(512, 2) void ln_f32(const float* __restrict__ x,
                                                 const float* __restrict__ g,
                                                 const float* __restrict__ beta,
                                                 u16* __restrict__ out) {
  const int tid = threadIdx.x;
  const size_t base = (size_t)blockIdx.x * 32768;
  float4 v[16];
  float s = 0.f, ss = 0.f;
#pragma unroll
  for (int j = 0; j < 16; ++j) {
    v[j] = *(const float4*)(x + base + tid * 4 + j * 2048);
    s  += v[j].x + v[j].y + v[j].z + v[j].w;
    ss += v[j].x * v[j].x + v[j].y * v[j].y + v[j].z * v[j].z + v[j].w * v[j].w;
  }
#pragma unroll
  for (int off = 32; off > 0; off >>= 1) {
    s += __shfl_down(s, off, 64);
    ss += __shfl_down(ss, off, 64);
  }
  __shared__ float red[16];
  int wave = tid >> 6, lane = tid & 63;
  if (lane == 0) { red[wave] = s; red[8 + wave] = ss; }
  __syncthreads();
  float S = 0.f, SS = 0.f;
#pragma unroll
  for (int wv = 0; wv < 8; ++wv) { S += red[wv]; SS += red[8 + wv]; }
  const float inv = 1.0f / 32768.0f;
  float mu = S * inv;
  float rs = rsqrtf(SS * inv - mu * mu + 1e-5f);
#pragma unroll
  for (int j = 0; j < 16; ++j) {
    const int i = tid * 4 + j * 2048;
    float4 gv = *(const float4*)(g + i);
    float4 bv = *(const float4*)(beta + i);
    uint2 o;
    o.x = (unsigned)f2bf((v[j].x - mu) * rs * gv.x + bv.x) |
          ((unsigned)f2bf((v[j].y - mu) * rs * gv.y + bv.y) << 16);
    o.y = (unsigned)f2bf((v[j].z - mu) * rs * gv.z + bv.z) |
          ((unsigned)f2bf((v[j].w - mu) * rs * gv.w + bv.w) << 16);
    *(uint2*)(out + base + i) = o;
  }
}

// ---------------- LayerNorm [64,512] slab, bf16 in, single global read
__global__ __launch_bounds__(512, 2) void ln_bf16(const u16* __restrict__ x,
                                                  const float* __restrict__ g,
                                                  const float* __restrict__ beta,
                                                  u16* __restrict__ out) {
  const int tid = threadIdx.x;
  const size_t base = (size_t)blockIdx.x * 32768;
  uint4 v[8];
  float s = 0.f, ss = 0.f;
#pragma unroll
  for (int j = 0; j < 8; ++j) {
    v[j] = *(const uint4*)(x + base + tid * 8 + j * 4096);
    const unsigned* a = &v[j].x;
#pragma unroll
    for (int t = 0; t < 4; ++t) {
      float lo = bf2f((u16)(a[t] & 0xffff)), hi = bf2f((u16)(a[t] >> 16));
      s += lo + hi; ss += lo * lo + hi * hi;
    }
  }
#pragma unroll
  for (int off = 32; off > 0; off >>= 1) {
    s += __shfl_down(s, off, 64);
    ss += __shfl_down(ss, off, 64);
  }
  __shared__ float red[16];
  int wave = tid >> 6, lane = tid & 63;
  if (lane == 0) { red[wave] = s; red[8 + wave] = ss; }
  __syncthreads();
  float S = 0.f, SS = 0.f;
#pragma unroll
  for (int wv = 0; wv < 8; ++wv) { S += red[wv]; SS += red[8 + wv]; }
  const float inv = 1.0f / 32768.0f;
  float mu = S * inv;
  float rs = rsqrtf(SS * inv - mu * mu + 1e-5f);
#pragma unroll
  for (int j = 0; j < 8; ++j) {
    const int i = tid * 8 + j * 4096;
    const unsigned* a = &v[j].x;
    uint4 o;
    unsigned* ov = &o.x;
#pragma unroll
    for (int t = 0; t < 4; ++t) {
      float lo = bf2f((u16)(a[t] & 0xffff)), hi = bf2f((u16)(a[t] >> 16));
      float4 gv2; float2 bv2;
      float glo = g[i + 2 * t], ghi = g[i + 2 * t + 1];
      float blo = beta[i + 2 * t], bhi = beta[i + 2 * t + 1];
      (void)gv2; (void)bv2;
      ov[t] = (unsigned)f2bf((lo - mu) * rs * glo + blo) |
              ((unsigned)f2bf((hi - mu) * rs * ghi + bhi) << 16);
    }
    *(uint4*)(out + base + i) = o;
  }
}

// ---------------- GEMM: C[M,N] = A[M,K](bf16) @ Bt[N,K](bf16)^T, BK=64
// LDS row = 64 u16 (128 B), 8 16B chunks; slot s of row r holds global chunk
// s ^ (r&7). Staging is lane-linear (async16-safe: addr = tid*16 B);
// fragment reads land 2 lanes/bank-group (free).
// MODE 0: plain, bf16 out   MODE 1: +bias, ReLU, bf16 out
// MODE 2: +bias, +resid(fp32), fp32 out
template <int MODE>
__global__ __launch_bounds__(256, 4) void gemm_bt(
    const u16* __restrict__ A, const u16* __restrict__ Bt,
    const float* __restrict__ bias, const float* __restrict__ resid,
    float* __restrict__ Cf, u16* __restrict__ Cb, int M, int N, int K) {
  __shared__ u16 As[128 * 64];
  __shared__ u16 Bs[128 * 64];
  const int tid = threadIdx.x;
  const int wave = tid >> 6, lane = tid & 63;
  const int quad = lane >> 4, l16 = lane & 15;
  const int wm = (wave >> 1) * 64, wn = (wave & 1) * 64;
  const int m0 = blockIdx.x * 128, n0 = blockIdx.y * 128;

  f32x4 acc[4][4];
#pragma unroll
  for (int i = 0; i < 4; ++i)
#pragma unroll
    for (int j = 0; j < 4; ++j) acc[i][j] = (f32x4){0.f, 0.f, 0.f, 0.f};

  const int rbase = tid >> 3;                     // 0..31
  const int slot  = tid & 7;                      // 16B slot in row
  const int gcol  = (slot ^ (rbase & 7)) * 8;     // swizzled source col (u16)
  const int lofs  = tid * 8;                      // u16 units = rbase*64+slot*8

  const u16* ag = A + (size_t)(m0 + rbase) * K + gcol;
  const u16* bg = Bt + (size_t)(n0 + rbase) * K + gcol;
  const int swr = (l16 & 7);                      // read-side row swizzle bits

  for (int k0 = 0; k0 < K; k0 += 64) {
    __syncthreads();
#pragma unroll
    for (int j = 0; j < 4; ++j) {
      async16(ag + (size_t)(32 * j) * K + k0, &As[lofs + j * 2048]);
      async16(bg + (size_t)(32 * j) * K + k0, &Bs[lofs + j * 2048]);
    }
    __syncthreads();
#pragma unroll
    for (int h = 0; h < 2; ++h) {
      const int sw = (((h << 2) + quad) ^ swr) * 8;
      bf16x8 af[4], bfr[4];
#pragma unroll
      for (int i = 0; i < 4; ++i)
        af[i] = *(const bf16x8*)&As[(wm + i * 16 + l16) * 64 + sw];
#pragma unroll
      for (int j = 0; j < 4; ++j)
        bfr[j] = *(const bf16x8*)&Bs[(wn + j * 16 + l16) * 64 + sw];
#pragma unroll
      for (int i = 0; i < 4; ++i)
#pragma unroll
        for (int j = 0; j < 4; ++j)
          acc[i][j] = __builtin_amdgcn_mfma_f32_16x16x32_bf16(af[i], bfr[j],
                                                              acc[i][j], 0, 0, 0);
    }
  }

#pragma unroll
  for (int j = 0; j < 4; ++j) {
    const int col = n0 + wn + j * 16 + l16;
    float bj = 0.f;
    if (MODE >= 1) bj = bias[col];
#pragma unroll
    for (int i = 0; i < 4; ++i) {
      const int rowb = m0 + wm + i * 16 + quad * 4;
#pragma unroll
      for (int r = 0; r < 4; ++r) {
        float v = acc[i][j][r] + bj;
        if (MODE == 1) v = fmaxf(v, 0.f);
        size_t idx = (size_t)(rowb + r) * N + col;
        if (MODE == 2) { v += resid[idx]; Cf[idx] = v; }
        else           Cb[idx] = f2bf(v);
      }
    }
  }
}

extern "C" void kernel_launch(void* const* d_in, const int* in_sizes, int n_in,
                              void* d_out, int out_size, void* d_ws,
                              size_t ws_size, hipStream_t stream) {
  const float* x    = (const float*)d_in[0];  // [512,64,512] fp32
  const float* w    = (const float*)d_in[1];  // [1,512]
  const float* ln1w = (const float*)d_in[2];  // [64,512]
  const float* ln1b = (const float*)d_in[3];
  const float* ln2w = (const float*)d_in[4];
  const float* ln2b = (const float*)d_in[5];
  const float* w1   = (const float*)d_in[6];  // [512,2048]
  const float* b1   = (const float*)d_in[7];  // [2048]
  const float* w2   = (const float*)d_in[8];  // [2048,512]
  const float* b2   = (const float*)d_in[9];  // [512]
  float* out = (float*)d_out;                 // [512,64,512] fp32

  char* ws = (char*)d_ws;
  // y overlaps h1+h2 (both dead before FFN1 writes y)
  u16*   y   = (u16*)(ws);                  // [32768,2048] bf16  134,217,728 B @ 0
  u16*   h1  = (u16*)(ws);                  // [32768,512]  bf16   33,554,432 B @ 0
  u16*   h2  = (u16*)(ws + 33554432);       // [32768,512]  bf16   33,554,432 B
  u16*   h3  = (u16*)(ws + 134217728);      // [32768,512]  bf16   33,554,432 B
  u16*   ct  = (u16*)(ws + 167772160);      // [512,512]    bf16      524,288 B
  u16*   w1t = (u16*)(ws + 168296448);      // [2048,512]   bf16    2,097,152 B
  u16*   w2t = (u16*)(ws + 170393600);      // [512,2048]   bf16    2,097,152 B
  // peak ws use: 172,490,752 B

  build_ct<<<1024, 256, 0, stream>>>(w, ct);
  transpose_w<<<dim3(64, 16), 256, 0, stream>>>(w1, w1t, 512, 2048);
  transpose_w<<<dim3(16, 64), 256, 0, stream>>>(w2, w2t, 2048, 512);

  // LN1: x(fp32) -> h1(bf16), single global read
  ln_f32<<<512, 512, 0, stream>>>(x, ln1w, ln1b, h1);
  // freq filter: h2(bf16) = h1 @ C
  gemm_bt<0><<<dim3(256, 4), 256, 0, stream>>>(h1, ct, nullptr, nullptr,
                                               nullptr, h2, 32768, 512, 512);
  // LN2: h2(bf16) -> h3(bf16)
  ln_bf16<<<512, 512, 0, stream>>>(h2, ln2w, ln2b, h3);
  // FFN1: y(bf16) = relu(h3 @ w1 + b1)
  gemm_bt<1><<<dim3(256, 16), 256, 0, stream>>>(h3, w1t, b1, nullptr,
                                                nullptr, y, 32768, 2048, 512);
  // FFN2 + residual: out(fp32) = y @ w2 + b2 + x
  gemm_bt<2><<<dim3(256, 4), 256, 0, stream>>>(y, w2t, b2, x,
                                               out, nullptr, 32768, 512, 2048);
}